// Round 2
// baseline (264.540 us; speedup 1.0000x reference)
//
#include <hip/hip_runtime.h>
#include <hip/hip_bf16.h>

typedef __attribute__((ext_vector_type(8))) short short8;
typedef __attribute__((ext_vector_type(4))) float f32x4;

#define NB 4        // batch
#define NC 64       // in_channels C
#define NCI 32      // inter_channels CI
#define NH 96
#define NW 96
#define NN (NH*NW)      // 9216
#define NM ((NH/2)*(NW/2)) // 2304

// ---------------------------------------------------------------------------
// conv1x1: out[b][n][o] = sum_k w[o][k]*in[b][k][n] + bias[o]   (o = 0..63)
// in: [B][Cin][N] fp32, out: [B][N][64] bf16.  grid (N/64, B), block 256.
// ---------------------------------------------------------------------------
__global__ __launch_bounds__(256) void conv_nc(
    const float* __restrict__ in, const float* __restrict__ w,
    const float* __restrict__ bias, __hip_bfloat16* __restrict__ out, int Cin) {
  __shared__ __align__(16) float xs[64][64]; // [k][n_local]
  __shared__ float wl[64][65];               // [o][k]
  int b = blockIdx.y;
  int n0 = blockIdx.x * 64;
  int t = threadIdx.x;

  for (int i = t; i < 64 * Cin; i += 256) {
    int o = i / Cin; int k = i - o * Cin;
    wl[o][k] = w[i];
  }
  for (int i = t; i < Cin * 16; i += 256) {
    int k = i >> 4, seg = i & 15;
    *(float4*)&xs[k][seg * 4] =
        *(const float4*)(in + ((size_t)b * Cin + k) * NN + n0 + seg * 4);
  }
  __syncthreads();

  int nl = t >> 2, cg = t & 3; // thread covers o = cg*16..cg*16+15 at n = n0+nl
  float acc[16];
#pragma unroll
  for (int i = 0; i < 16; ++i) acc[i] = bias[cg * 16 + i];
  for (int k = 0; k < Cin; ++k) {
    float xv = xs[k][nl];
#pragma unroll
    for (int i = 0; i < 16; ++i) acc[i] += wl[cg * 16 + i][k] * xv;
  }
  __align__(16) __hip_bfloat16 tmp[16];
#pragma unroll
  for (int i = 0; i < 16; ++i) tmp[i] = __float2bfloat16(acc[i]);
  size_t ob = ((size_t)b * NN + n0 + nl) * 64 + cg * 16;
  *(uint4*)(out + ob) = *(uint4*)&tmp[0];
  *(uint4*)(out + ob + 8) = *(uint4*)&tmp[8];
}

// ---------------------------------------------------------------------------
// 2x2 maxpool of gfull/phifull ([B][N][64] bf16, n-major) ->
//   Gcm  [B][64][M]  (m contiguous, PV B-frag layout)
//   PhiT [B][M][64]  (c contiguous, QK B-frag layout)
// ---------------------------------------------------------------------------
__global__ __launch_bounds__(256) void pool_k(
    const __hip_bfloat16* __restrict__ gfull, const __hip_bfloat16* __restrict__ phifull,
    __hip_bfloat16* __restrict__ Gcm, __hip_bfloat16* __restrict__ PhiT) {
  int idx = blockIdx.x * 256 + threadIdx.x;
  int c = idx & 63;
  int mm = idx >> 6;
  int m = mm % NM;
  int b = mm / NM;
  int i = m / (NW / 2), j = m - i * (NW / 2);
  size_t base = ((size_t)b * NN + (2 * i) * NW + 2 * j) * 64 + c;
  float g0 = (float)gfull[base];
  g0 = fmaxf(g0, (float)gfull[base + 64]);
  g0 = fmaxf(g0, (float)gfull[base + (size_t)NW * 64]);
  g0 = fmaxf(g0, (float)gfull[base + (size_t)(NW + 1) * 64]);
  float p0 = (float)phifull[base];
  p0 = fmaxf(p0, (float)phifull[base + 64]);
  p0 = fmaxf(p0, (float)phifull[base + (size_t)NW * 64]);
  p0 = fmaxf(p0, (float)phifull[base + (size_t)(NW + 1) * 64]);
  Gcm[((size_t)b * 64 + c) * NM + m] = __float2bfloat16(g0);
  PhiT[((size_t)b * NM + m) * 64 + c] = __float2bfloat16(p0);
}

// ---------------------------------------------------------------------------
// Fused attention + residual + W-conv.
// grid (144, B), block 256 (4 waves); wave handles 16 n-rows.
// z2[b][o][n] fp32 out.
// ---------------------------------------------------------------------------
__global__ __launch_bounds__(256) void attn_k(
    const __hip_bfloat16* __restrict__ Theta, const __hip_bfloat16* __restrict__ PhiT,
    const __hip_bfloat16* __restrict__ Gcm, const float* __restrict__ x,
    const float* __restrict__ Ww, const float* __restrict__ Wb,
    float* __restrict__ z2) {
  __shared__ __align__(16) __hip_bfloat16 phis[32][72];   // [m_local][c]
  __shared__ __align__(16) __hip_bfloat16 gs[64][40];     // [c][m_local]
  __shared__ __align__(16) __hip_bfloat16 pbuf[4][16][40];// per-wave P [n_local][m_local]
  __shared__ float wls[32][65];                           // W_w fp32
  __shared__ float z1s[4][16][68];                        // per-wave z1 [n_local][c]

  int t = threadIdx.x;
  int wave = t >> 6, lane = t & 63;
  int l15 = lane & 15, quad = lane >> 4;
  int b = blockIdx.y;
  int n0 = blockIdx.x * 64 + wave * 16;

  for (int i = t; i < 32 * 64; i += 256) wls[i >> 6][i & 63] = Ww[i];

  // A-frags: Theta rows n0+l15, k = quad*8+j  (A[m=lane&15][k=quad*8+j])
  const __hip_bfloat16* trow = Theta + ((size_t)b * NN + n0 + l15) * 64 + quad * 8;
  short8 ta0 = *(const short8*)trow;         // c 0..31
  short8 ta1 = *(const short8*)(trow + 32);  // c 32..63

  f32x4 acc[4];
#pragma unroll
  for (int cb = 0; cb < 4; ++cb) acc[cb] = (f32x4){0.f, 0.f, 0.f, 0.f};
  float rsum[4] = {0.f, 0.f, 0.f, 0.f};

  const __hip_bfloat16* phibase = PhiT + (size_t)b * NM * 64;
  const __hip_bfloat16* gbase = Gcm + (size_t)b * 64 * NM;

  for (int ch = 0; ch < NM / 32; ++ch) {  // 72 chunks
    int m0 = ch * 32;
    __syncthreads();
    {   // stage Phi chunk: 32 rows x 64 c
      int r = t >> 3, seg = t & 7;
      *(uint4*)&phis[r][seg * 8] = *(const uint4*)(phibase + (size_t)(m0 + r) * 64 + seg * 8);
    }
    {   // stage G chunk: 64 rows x 32 m
      int r = t >> 2, seg = t & 3;
      *(uint4*)&gs[r][seg * 8] = *(const uint4*)(gbase + (size_t)r * NM + m0 + seg * 8);
    }
    __syncthreads();

#pragma unroll
    for (int tm = 0; tm < 2; ++tm) {
      // B-frag: B[k=quad*8+j][n=l15] = Phi[m0+tm*16+l15][k]
      short8 pb0 = *(const short8*)&phis[tm * 16 + l15][quad * 8];
      short8 pb1 = *(const short8*)&phis[tm * 16 + l15][32 + quad * 8];
      f32x4 s = (f32x4){0.f, 0.f, 0.f, 0.f};
      s = __builtin_amdgcn_mfma_f32_16x16x32_bf16(ta0, pb0, s, 0, 0, 0);
      s = __builtin_amdgcn_mfma_f32_16x16x32_bf16(ta1, pb1, s, 0, 0, 0);
      // D layout: row(n_local)=quad*4+r, col(m_local)=tm*16+l15
#pragma unroll
      for (int r = 0; r < 4; ++r) {
        float e = __expf(s[r]);     // logits bounded (weights ~0.05): no max-sub needed
        rsum[r] += e;
        pbuf[wave][quad * 4 + r][tm * 16 + l15] = __float2bfloat16(e);
      }
    }
    // PV: A-frag from pbuf (same wave, lockstep)
    short8 pa = *(const short8*)&pbuf[wave][l15][quad * 8];
#pragma unroll
    for (int cb = 0; cb < 4; ++cb) {
      short8 gb = *(const short8*)&gs[cb * 16 + l15][quad * 8]; // B[k=m][n=c]
      acc[cb] = __builtin_amdgcn_mfma_f32_16x16x32_bf16(pa, gb, acc[cb], 0, 0, 0);
    }
  }

  // rowsum reduce across the 16 lanes of each quad-group
  float rinv[4];
#pragma unroll
  for (int r = 0; r < 4; ++r) {
    float v = rsum[r];
    v += __shfl_xor(v, 1); v += __shfl_xor(v, 2);
    v += __shfl_xor(v, 4); v += __shfl_xor(v, 8);
    rinv[r] = 1.0f / v;
  }

  // z1 = y/rowsum + x  -> per-wave LDS [n_local][c]  (x fp32)
  const float* xb = x + (size_t)b * 64 * NN;
#pragma unroll
  for (int cb = 0; cb < 4; ++cb) {
    int c = cb * 16 + l15;
#pragma unroll
    for (int r = 0; r < 4; ++r) {
      float y = acc[cb][r] * rinv[r] + xb[(size_t)c * NN + n0 + quad * 4 + r];
      z1s[wave][quad * 4 + r][c] = y;
    }
  }

  // W conv: z2[o][n] = sum_c Ww[o][c]*z1[c][n] + Wb[o]; lane: n = n0+l15, o = quad*8+j
  float s[8];
#pragma unroll
  for (int j = 0; j < 8; ++j) s[j] = Wb[quad * 8 + j];
  for (int c = 0; c < 64; ++c) {
    float zv = z1s[wave][l15][c];
#pragma unroll
    for (int j = 0; j < 8; ++j) s[j] += wls[quad * 8 + j][c] * zv;
  }
  float* z2b = z2 + (size_t)b * NCI * NN;
#pragma unroll
  for (int j = 0; j < 8; ++j) z2b[(size_t)(quad * 8 + j) * NN + n0 + l15] = s[j];
}

// ---------------------------------------------------------------------------
// BN batch stats -> per-channel scale/shift.  grid 32 blocks (one per channel).
// ---------------------------------------------------------------------------
__global__ __launch_bounds__(256) void bn_stats(
    const float* __restrict__ z2, const float* __restrict__ gamma,
    const float* __restrict__ beta, float* __restrict__ ss) {
  int o = blockIdx.x;
  int t = threadIdx.x;
  float s = 0.f, s2 = 0.f;
  for (int b = 0; b < NB; ++b) {
    const float* p = z2 + (size_t)(b * NCI + o) * NN;
    for (int n = t; n < NN; n += 256) {
      float v = p[n];
      s += v; s2 += v * v;
    }
  }
#pragma unroll
  for (int off = 1; off < 64; off <<= 1) {
    s += __shfl_xor(s, off);
    s2 += __shfl_xor(s2, off);
  }
  __shared__ float r1[4], r2[4];
  int wave = t >> 6;
  if ((t & 63) == 0) { r1[wave] = s; r2[wave] = s2; }
  __syncthreads();
  if (t == 0) {
    float S = r1[0] + r1[1] + r1[2] + r1[3];
    float S2 = r2[0] + r2[1] + r2[2] + r2[3];
    const float inv = 1.0f / (float)(NB * NN);
    float mean = S * inv;
    float var = S2 * inv - mean * mean;
    float sc = gamma[o] * rsqrtf(var + 1e-5f);
    ss[o] = sc;
    ss[32 + o] = beta[o] - mean * sc;
  }
}

__global__ __launch_bounds__(256) void bn_apply(
    const float* __restrict__ z2, const float* __restrict__ ss,
    float* __restrict__ out) {
  int co = blockIdx.y;           // b*32+o
  int o = co & 31;
  int n = blockIdx.x * 256 + threadIdx.x;
  size_t idx = (size_t)co * NN + n;
  out[idx] = z2[idx] * ss[o] + ss[32 + o];
}

// ---------------------------------------------------------------------------
extern "C" void kernel_launch(void* const* d_in, const int* in_sizes, int n_in,
                              void* d_out, int out_size, void* d_ws, size_t ws_size,
                              hipStream_t stream) {
  const float* x       = (const float*)d_in[0];
  const float* feature = (const float*)d_in[1];
  const float* g_w     = (const float*)d_in[2];
  const float* g_b     = (const float*)d_in[3];
  const float* theta_w = (const float*)d_in[4];
  const float* theta_b = (const float*)d_in[5];
  const float* phi_w   = (const float*)d_in[6];
  const float* phi_b   = (const float*)d_in[7];
  const float* W_w     = (const float*)d_in[8];
  const float* W_b     = (const float*)d_in[9];
  const float* bn_g    = (const float*)d_in[10];
  const float* bn_b    = (const float*)d_in[11];

  char* ws = (char*)d_ws;
  const size_t szNC = (size_t)NB * NN * 64 * sizeof(__hip_bfloat16); // 4,718,592
  const size_t szM  = (size_t)NB * 64 * NM * sizeof(__hip_bfloat16); // 1,179,648
  __hip_bfloat16* Theta   = (__hip_bfloat16*)(ws);
  __hip_bfloat16* Gfull   = (__hip_bfloat16*)(ws + szNC);
  __hip_bfloat16* Phifull = (__hip_bfloat16*)(ws + 2 * szNC);
  __hip_bfloat16* Gcm     = (__hip_bfloat16*)(ws + 3 * szNC);
  __hip_bfloat16* PhiT    = (__hip_bfloat16*)(ws + 3 * szNC + szM);
  // z2 aliases Gfull/Phifull (dead after pool_k): 4*32*9216*4 = 4.72 MB < 9.44 MB
  float*          z2      = (float*)(ws + szNC);
  float*          ss      = (float*)(ws + 3 * szNC + 2 * szM);

  dim3 blk(256);
  conv_nc<<<dim3(NN / 64, NB), blk, 0, stream>>>(x, theta_w, theta_b, Theta, 64);
  conv_nc<<<dim3(NN / 64, NB), blk, 0, stream>>>(x, g_w, g_b, Gfull, 64);
  conv_nc<<<dim3(NN / 64, NB), blk, 0, stream>>>(feature, phi_w, phi_b, Phifull, 32);
  pool_k<<<dim3((NB * NM * 64) / 256), blk, 0, stream>>>(Gfull, Phifull, Gcm, PhiT);
  attn_k<<<dim3(NN / 64, NB), blk, 0, stream>>>(Theta, PhiT, Gcm, x, W_w, W_b, z2);
  bn_stats<<<dim3(NCI), blk, 0, stream>>>(z2, bn_g, bn_b, ss);
  bn_apply<<<dim3(NN / 256, NB * NCI), blk, 0, stream>>>(z2, ss, (float*)d_out);
}

// Round 3
// 219.232 us; speedup vs baseline: 1.2067x; 1.2067x over previous
//
#include <hip/hip_runtime.h>
#include <hip/hip_bf16.h>

typedef __attribute__((ext_vector_type(8))) short short8;
typedef __attribute__((ext_vector_type(4))) float f32x4;

#define NB 4        // batch
#define NC 64       // in_channels C
#define NCI 32      // inter_channels CI
#define NH 96
#define NW 96
#define NN (NH*NW)         // 9216
#define NM ((NH/2)*(NW/2)) // 2304

__device__ inline unsigned pk2(float a, float b) {
  __hip_bfloat16 ha = __float2bfloat16(a), hb = __float2bfloat16(b);
  return (unsigned)*(unsigned short*)&ha | ((unsigned)*(unsigned short*)&hb << 16);
}
__device__ inline float ubf(unsigned u) {  // low 16 bits = bf16
  unsigned x = u << 16; return *(float*)&x;
}
__device__ inline short8 pack8(const float* v) {
  short8 s;
#pragma unroll
  for (int j = 0; j < 8; ++j) { __hip_bfloat16 h = __float2bfloat16(v[j]); s[j] = *(short*)&h; }
  return s;
}

// ---------------------------------------------------------------------------
// conv1x1 via MFMA, no LDS. out[b][n][o] = sum_c w[o][c]*x[b][c][n] + bias[o].
// A = weights (rows o, regs), B = x (cols n, strided-coalesced loads).
// D[o][n]: row=o=q*4+r, col=n=l15  ->  pack o-pairs, b32 stores.
// grid (NN/64, B), block 256 (4 waves x 16 n).
// ---------------------------------------------------------------------------
template<int KF, int NMAT>
__global__ __launch_bounds__(256) void conv_mfma(
    const float* __restrict__ xin, int Cin,
    const float* __restrict__ w0, const float* __restrict__ b0, __hip_bfloat16* __restrict__ o0,
    const float* __restrict__ w1, const float* __restrict__ b1, __hip_bfloat16* __restrict__ o1) {
  int t = threadIdx.x, wv = t >> 6, lane = t & 63, l15 = lane & 15, q = lane >> 4;
  int b = blockIdx.y;
  int nb = blockIdx.x * 64 + wv * 16;

  // weight A-frags: A[o=l15(+ot*16)][k=c=kf*32+q*8+j]
  short8 wa0[4][KF], wa1[4][KF];
  float tmp[8];
#pragma unroll
  for (int ot = 0; ot < 4; ++ot)
#pragma unroll
    for (int kf = 0; kf < KF; ++kf) {
      const float* p = w0 + (size_t)(ot * 16 + l15) * Cin + kf * 32 + q * 8;
      *(float4*)&tmp[0] = *(const float4*)p;
      *(float4*)&tmp[4] = *(const float4*)(p + 4);
      wa0[ot][kf] = pack8(tmp);
      if (NMAT == 2) {
        const float* p1 = w1 + (size_t)(ot * 16 + l15) * Cin + kf * 32 + q * 8;
        *(float4*)&tmp[0] = *(const float4*)p1;
        *(float4*)&tmp[4] = *(const float4*)(p1 + 4);
        wa1[ot][kf] = pack8(tmp);
      }
    }

  // x B-frags: B[k=c][n=l15]
  short8 bx[KF];
#pragma unroll
  for (int kf = 0; kf < KF; ++kf) {
#pragma unroll
    for (int j = 0; j < 8; ++j)
      tmp[j] = xin[((size_t)b * Cin + kf * 32 + q * 8 + j) * NN + nb + l15];
    bx[kf] = pack8(tmp);
  }

#pragma unroll
  for (int mat = 0; mat < NMAT; ++mat) {
    const float* bias = (mat == 0) ? b0 : b1;
    __hip_bfloat16* out = (mat == 0) ? o0 : o1;
#pragma unroll
    for (int ot = 0; ot < 4; ++ot) {
      f32x4 d;
#pragma unroll
      for (int r = 0; r < 4; ++r) d[r] = bias[ot * 16 + q * 4 + r];
      d = __builtin_amdgcn_mfma_f32_16x16x32_bf16((mat == 0) ? wa0[ot][0] : wa1[ot][0], bx[0], d, 0, 0, 0);
      if (KF > 1)
        d = __builtin_amdgcn_mfma_f32_16x16x32_bf16((mat == 0) ? wa0[ot][1] : wa1[ot][1], bx[1], d, 0, 0, 0);
      size_t base = ((size_t)b * NN + nb + l15) * 64 + ot * 16 + q * 4;
      *(unsigned*)(out + base) = pk2(d[0], d[1]);
      *(unsigned*)(out + base + 2) = pk2(d[2], d[3]);
    }
  }
}

// ---------------------------------------------------------------------------
// 2x2 maxpool ([B][N][64] bf16, n-major) -> Gcm [B][64][M], PhiT [B][M][64]
// ---------------------------------------------------------------------------
__global__ __launch_bounds__(256) void pool_k(
    const __hip_bfloat16* __restrict__ gfull, const __hip_bfloat16* __restrict__ phifull,
    __hip_bfloat16* __restrict__ Gcm, __hip_bfloat16* __restrict__ PhiT) {
  int idx = blockIdx.x * 256 + threadIdx.x;
  int c = idx & 63;
  int mm = idx >> 6;
  int m = mm % NM;
  int b = mm / NM;
  int i = m / (NW / 2), j = m - i * (NW / 2);
  size_t base = ((size_t)b * NN + (2 * i) * NW + 2 * j) * 64 + c;
  float g0 = (float)gfull[base];
  g0 = fmaxf(g0, (float)gfull[base + 64]);
  g0 = fmaxf(g0, (float)gfull[base + (size_t)NW * 64]);
  g0 = fmaxf(g0, (float)gfull[base + (size_t)(NW + 1) * 64]);
  float p0 = (float)phifull[base];
  p0 = fmaxf(p0, (float)phifull[base + 64]);
  p0 = fmaxf(p0, (float)phifull[base + (size_t)NW * 64]);
  p0 = fmaxf(p0, (float)phifull[base + (size_t)(NW + 1) * 64]);
  Gcm[((size_t)b * 64 + c) * NM + m] = __float2bfloat16(g0);
  PhiT[((size_t)b * NM + m) * 64 + c] = __float2bfloat16(p0);
}

// ---------------------------------------------------------------------------
// Fused attention + residual + W-conv (MFMA).  grid (144, B), block 256.
// Waves own disjoint 32-m slices of a 128-m staged superchunk.
// S^T = Phi·Theta^T  (C/D m-runs per lane -> packed b32 P writes, [n][m] pbuf)
// z2[b][n][32] fp32 out.
// ---------------------------------------------------------------------------
__global__ __launch_bounds__(256) void attn_k(
    const __hip_bfloat16* __restrict__ Theta, const __hip_bfloat16* __restrict__ PhiT,
    const __hip_bfloat16* __restrict__ Gcm, const float* __restrict__ x,
    const float* __restrict__ Ww, const float* __restrict__ Wb,
    float* __restrict__ z2) {
  struct SMem {
    union {
      struct { __hip_bfloat16 phis[128][72]; __hip_bfloat16 gs[64][136]; } a;  // 35840 B
      __hip_bfloat16 zpart[4][64][68];                                         // 34816 B
    } u1;
    union {
      __hip_bfloat16 pbuf[4][64][40];   // 20480 B  [wave][n][m] (stride 40: 16B rows)
      __hip_bfloat16 zacc[64][72];      //  9216 B  [n][c]
    } u2;
    float rs[4][64];
  };
  __shared__ SMem sm;

  int t = threadIdx.x;
  int wv = t >> 6, lane = t & 63;
  int l15 = lane & 15, q = lane >> 4;
  int b = blockIdx.y;
  int n0 = blockIdx.x * 64;

  // Theta B-frags (held all kernel): B[k=c][n=l15]  (rows n0..n0+63)
  short8 tb[4][2];
#pragma unroll
  for (int nt = 0; nt < 4; ++nt)
#pragma unroll
    for (int kf = 0; kf < 2; ++kf)
      tb[nt][kf] = *(const short8*)(Theta + ((size_t)b * NN + n0 + nt * 16 + l15) * 64 + kf * 32 + q * 8);

  // Ww B-frags for the W-conv epilogue: B[k=c][o=l15] (fp32 -> bf16)
  short8 wb[2][2];
  {
    float tmp[8];
#pragma unroll
    for (int ot = 0; ot < 2; ++ot)
#pragma unroll
      for (int kf = 0; kf < 2; ++kf) {
        const float* p = Ww + (size_t)(ot * 16 + l15) * 64 + kf * 32 + q * 8;
        *(float4*)&tmp[0] = *(const float4*)p;
        *(float4*)&tmp[4] = *(const float4*)(p + 4);
        wb[ot][kf] = pack8(tmp);
      }
  }

  f32x4 acc[4][4];
#pragma unroll
  for (int nt = 0; nt < 4; ++nt)
#pragma unroll
    for (int ct = 0; ct < 4; ++ct) acc[nt][ct] = (f32x4){0.f, 0.f, 0.f, 0.f};
  float rsum[4] = {0.f, 0.f, 0.f, 0.f};

  const __hip_bfloat16* phibase = PhiT + (size_t)b * NM * 64;
  const __hip_bfloat16* gbase = Gcm + (size_t)b * 64 * NM;

  for (int sc = 0; sc < NM / 128; ++sc) {  // 18 superchunks of 128 m
    int m0 = sc * 128;
    __syncthreads();
    // stage Phi: 128 rows x 64 c  (16 KB)
#pragma unroll
    for (int p = 0; p < 4; ++p) {
      int idx = p * 256 + t, r = idx >> 3, seg = idx & 7;
      *(uint4*)&sm.u1.a.phis[r][seg * 8] = *(const uint4*)(phibase + (size_t)(m0 + r) * 64 + seg * 8);
    }
    // stage G: 64 rows x 128 m  (16 KB)
#pragma unroll
    for (int p = 0; p < 4; ++p) {
      int idx = p * 256 + t, c = idx >> 4, seg = idx & 15;
      *(uint4*)&sm.u1.a.gs[c][seg * 8] = *(const uint4*)(gbase + (size_t)c * NM + m0 + seg * 8);
    }
    __syncthreads();

    // A-frags Phi (this wave's 32-m slice): A[m=l15][k=c]
    short8 pha[2][2];
#pragma unroll
    for (int mt = 0; mt < 2; ++mt)
#pragma unroll
      for (int kf = 0; kf < 2; ++kf)
        pha[mt][kf] = *(const short8*)&sm.u1.a.phis[wv * 32 + mt * 16 + l15][kf * 32 + q * 8];
    // G B-frags: B[k=m][c=l15]
    short8 gb[4];
#pragma unroll
    for (int ct = 0; ct < 4; ++ct)
      gb[ct] = *(const short8*)&sm.u1.a.gs[ct * 16 + l15][wv * 32 + q * 8];

#pragma unroll
    for (int nt = 0; nt < 4; ++nt) {
#pragma unroll
      for (int mt = 0; mt < 2; ++mt) {
        // S^T tile: D[m][n], row=m=q*4+r, col=n=l15
        f32x4 s = (f32x4){0.f, 0.f, 0.f, 0.f};
        s = __builtin_amdgcn_mfma_f32_16x16x32_bf16(pha[mt][0], tb[nt][0], s, 0, 0, 0);
        s = __builtin_amdgcn_mfma_f32_16x16x32_bf16(pha[mt][1], tb[nt][1], s, 0, 0, 0);
        float e0 = __expf(s[0]), e1 = __expf(s[1]), e2 = __expf(s[2]), e3 = __expf(s[3]);
        rsum[nt] += (e0 + e1) + (e2 + e3);
        __hip_bfloat16* pb = &sm.u2.pbuf[wv][nt * 16 + l15][mt * 16 + q * 4];
        *(unsigned*)pb = pk2(e0, e1);
        *(unsigned*)(pb + 2) = pk2(e2, e3);
      }
      // PV for this nt: A = P [n][k=m(32)], B = G
      short8 pf = *(const short8*)&sm.u2.pbuf[wv][nt * 16 + l15][q * 8];
#pragma unroll
      for (int ct = 0; ct < 4; ++ct)
        acc[nt][ct] = __builtin_amdgcn_mfma_f32_16x16x32_bf16(pf, gb[ct], acc[nt][ct], 0, 0, 0);
    }
  }

  // ---- rowsum: reduce over quads, share across waves ----
#pragma unroll
  for (int nt = 0; nt < 4; ++nt) {
    float v = rsum[nt];
    v += __shfl_xor(v, 16);
    v += __shfl_xor(v, 32);
    if (lane < 16) sm.rs[wv][nt * 16 + lane] = v;
  }
  __syncthreads();   // also: all waves done reading phis/gs (zpart aliases them)

  float rowinv[4][4];
#pragma unroll
  for (int nt = 0; nt < 4; ++nt) {
    float tot = sm.rs[0][nt * 16 + l15] + sm.rs[1][nt * 16 + l15] +
                sm.rs[2][nt * 16 + l15] + sm.rs[3][nt * 16 + l15];
    float rinv = 1.0f / tot;
#pragma unroll
    for (int r = 0; r < 4; ++r) rowinv[nt][r] = __shfl(rinv, q * 4 + r);
  }

  // ---- scaled partial y -> zpart[wave][n][c] (bf16) ----
#pragma unroll
  for (int nt = 0; nt < 4; ++nt)
#pragma unroll
    for (int ct = 0; ct < 4; ++ct)
#pragma unroll
      for (int r = 0; r < 4; ++r)
        sm.u1.zpart[wv][nt * 16 + q * 4 + r][ct * 16 + l15] =
            __float2bfloat16(acc[nt][ct][r] * rowinv[nt][r]);
  __syncthreads();

  // ---- final sum + residual: wave wv owns rows wv*16..wv*16+15 ----
  {
    int row = wv * 16 + l15;       // local n; lane covers c = q*16..q*16+15
    float z1v[16];
#pragma unroll
    for (int i = 0; i < 16; ++i)
      z1v[i] = x[((size_t)b * 64 + q * 16 + i) * NN + n0 + row];
#pragma unroll
    for (int wvv = 0; wvv < 4; ++wvv) {
#pragma unroll
      for (int j4 = 0; j4 < 4; ++j4) {
        uint2 p = *(const uint2*)&sm.u1.zpart[wvv][row][q * 16 + j4 * 4];
        z1v[j4 * 4 + 0] += ubf(p.x & 0xffffu);
        z1v[j4 * 4 + 1] += ubf(p.x >> 16);
        z1v[j4 * 4 + 2] += ubf(p.y & 0xffffu);
        z1v[j4 * 4 + 3] += ubf(p.y >> 16);
      }
    }
#pragma unroll
    for (int i2 = 0; i2 < 8; ++i2)
      *(unsigned*)&sm.u2.zacc[row][q * 16 + 2 * i2] = pk2(z1v[2 * i2], z1v[2 * i2 + 1]);
  }

  // ---- W-conv: z2[n][o] = zacc[n][c] · Ww^T[c][o] + Wb  (rows wv*16..+15) ----
  {
    short8 za[2];
#pragma unroll
    for (int kf = 0; kf < 2; ++kf)
      za[kf] = *(const short8*)&sm.u2.zacc[wv * 16 + l15][kf * 32 + q * 8];
#pragma unroll
    for (int ot = 0; ot < 2; ++ot) {
      float bias = Wb[ot * 16 + l15];
      f32x4 d = (f32x4){bias, bias, bias, bias};
      d = __builtin_amdgcn_mfma_f32_16x16x32_bf16(za[0], wb[ot][0], d, 0, 0, 0);
      d = __builtin_amdgcn_mfma_f32_16x16x32_bf16(za[1], wb[ot][1], d, 0, 0, 0);
#pragma unroll
      for (int r = 0; r < 4; ++r)
        z2[((size_t)b * NN + n0 + wv * 16 + q * 4 + r) * 32 + ot * 16 + l15] = d[r];
    }
  }
}

// ---------------------------------------------------------------------------
// BN: partial sums (96 blocks) -> finalize (1 block) -> apply (transpose).
// z2 layout [b][n][32].
// ---------------------------------------------------------------------------
__global__ __launch_bounds__(256) void bn_part(
    const float* __restrict__ z2, float* __restrict__ psum, float* __restrict__ psum2) {
  int t = threadIdx.x, o = t & 31, rg = t >> 5;
  int blk = blockIdx.x;
  const float* p = z2 + (size_t)blk * 384 * 32;
  float s = 0.f, s2 = 0.f;
  for (int it = 0; it < 48; ++it) {
    float v = p[(size_t)(it * 8 + rg) * 32 + o];
    s += v; s2 += v * v;
  }
  s += __shfl_xor(s, 32); s2 += __shfl_xor(s2, 32);
  __shared__ float r1[4][32], r2[4][32];
  int wv = t >> 6, lane = t & 63;
  if (lane < 32) { r1[wv][lane] = s; r2[wv][lane] = s2; }
  __syncthreads();
  if (t < 32) {
    float S = r1[0][t] + r1[1][t] + r1[2][t] + r1[3][t];
    float S2 = r2[0][t] + r2[1][t] + r2[2][t] + r2[3][t];
    psum[blk * 32 + t] = S;
    psum2[blk * 32 + t] = S2;
  }
}

__global__ void bn_fin(const float* __restrict__ psum, const float* __restrict__ psum2,
                       const float* __restrict__ gamma, const float* __restrict__ beta,
                       float* __restrict__ ss) {
  int t = threadIdx.x;
  if (t < 32) {
    float S = 0.f, S2 = 0.f;
    for (int k = 0; k < 96; ++k) { S += psum[k * 32 + t]; S2 += psum2[k * 32 + t]; }
    const float inv = 1.0f / (float)(NB * NN);
    float mean = S * inv;
    float var = S2 * inv - mean * mean;
    float sc = gamma[t] * rsqrtf(var + 1e-5f);
    ss[t] = sc;
    ss[32 + t] = beta[t] - mean * sc;
  }
}

__global__ __launch_bounds__(256) void bn_apply(
    const float* __restrict__ z2, const float* __restrict__ ss, float* __restrict__ out) {
  __shared__ float zt[32][65];
  int t = threadIdx.x;
  int b = blockIdx.y, n0 = blockIdx.x * 64;
#pragma unroll
  for (int it = 0; it < 2; ++it) {
    int idx = it * 256 + t, r = idx >> 3, seg = idx & 7;
    float4 v = *(const float4*)(z2 + ((size_t)b * NN + n0 + r) * 32 + seg * 4);
    zt[seg * 4 + 0][r] = v.x; zt[seg * 4 + 1][r] = v.y;
    zt[seg * 4 + 2][r] = v.z; zt[seg * 4 + 3][r] = v.w;
  }
  __syncthreads();
  int o = t >> 3, nseg = t & 7;
  float sc = ss[o], sh = ss[32 + o];
  float4 a, c;
  a.x = zt[o][nseg * 8 + 0] * sc + sh; a.y = zt[o][nseg * 8 + 1] * sc + sh;
  a.z = zt[o][nseg * 8 + 2] * sc + sh; a.w = zt[o][nseg * 8 + 3] * sc + sh;
  c.x = zt[o][nseg * 8 + 4] * sc + sh; c.y = zt[o][nseg * 8 + 5] * sc + sh;
  c.z = zt[o][nseg * 8 + 6] * sc + sh; c.w = zt[o][nseg * 8 + 7] * sc + sh;
  float* po = out + ((size_t)b * 32 + o) * NN + n0 + nseg * 8;
  *(float4*)po = a;
  *(float4*)(po + 4) = c;
}

// ---------------------------------------------------------------------------
extern "C" void kernel_launch(void* const* d_in, const int* in_sizes, int n_in,
                              void* d_out, int out_size, void* d_ws, size_t ws_size,
                              hipStream_t stream) {
  const float* x       = (const float*)d_in[0];
  const float* feature = (const float*)d_in[1];
  const float* g_w     = (const float*)d_in[2];
  const float* g_b     = (const float*)d_in[3];
  const float* theta_w = (const float*)d_in[4];
  const float* theta_b = (const float*)d_in[5];
  const float* phi_w   = (const float*)d_in[6];
  const float* phi_b   = (const float*)d_in[7];
  const float* W_w     = (const float*)d_in[8];
  const float* W_b     = (const float*)d_in[9];
  const float* bn_g    = (const float*)d_in[10];
  const float* bn_b    = (const float*)d_in[11];

  char* ws = (char*)d_ws;
  const size_t szNC = (size_t)NB * NN * 64 * sizeof(__hip_bfloat16); // 4,718,592
  const size_t szM  = (size_t)NB * 64 * NM * sizeof(__hip_bfloat16); // 1,179,648
  __hip_bfloat16* Theta   = (__hip_bfloat16*)(ws);
  __hip_bfloat16* Gfull   = (__hip_bfloat16*)(ws + szNC);
  __hip_bfloat16* Phifull = (__hip_bfloat16*)(ws + 2 * szNC);
  __hip_bfloat16* Gcm     = (__hip_bfloat16*)(ws + 3 * szNC);
  __hip_bfloat16* PhiT    = (__hip_bfloat16*)(ws + 3 * szNC + szM);
  // z2 [b][n][32] fp32 aliases Gfull (dead after pool_k): 4*9216*32*4 = 4,718,592 ✓
  float*          z2      = (float*)(ws + szNC);
  float*          ss      = (float*)(ws + 3 * szNC + 2 * szM);
  float*          psum    = ss + 64;
  float*          psum2   = psum + 96 * 32;

  dim3 blk(256);
  conv_mfma<2, 2><<<dim3(NN / 64, NB), blk, 0, stream>>>(x, 64, theta_w, theta_b, Theta,
                                                         g_w, g_b, Gfull);
  conv_mfma<1, 1><<<dim3(NN / 64, NB), blk, 0, stream>>>(feature, 32, phi_w, phi_b, Phifull,
                                                         nullptr, nullptr, nullptr);
  pool_k<<<dim3((NB * NM * 64) / 256), blk, 0, stream>>>(Gfull, Phifull, Gcm, PhiT);
  attn_k<<<dim3(NN / 64, NB), blk, 0, stream>>>(Theta, PhiT, Gcm, x, W_w, W_b, z2);
  bn_part<<<dim3(96), blk, 0, stream>>>(z2, psum, psum2);
  bn_fin<<<dim3(1), dim3(64), 0, stream>>>(psum, psum2, bn_g, bn_b, ss);
  bn_apply<<<dim3(NN / 64, NB), blk, 0, stream>>>(z2, ss, (float*)d_out);
}